// Round 1
// baseline (149.445 us; speedup 1.0000x reference)
//
#include <hip/hip_runtime.h>
#include <hip/hip_bf16.h>
#include <math.h>

// Problem constants
#define BB 2
#define HH 64
#define WW 64
#define DIMC 128
#define NH 4
#define HD 32
#define KS 7
#define DIL 2
#define NPIX (BB * HH * WW)      // 8192 rows
#define SCALE 0.17677669529663687f  // 32^-0.5

// ---------------------------------------------------------------------------
// GEMM: Y[r,c] = (sum_k X[r,k] * W[k,c] + b[c]) * scale
// X: [8192,128] f32, W: [128,128], b: [128]
// grid: 256 blocks (32 rows each), 256 threads
// ---------------------------------------------------------------------------
__global__ __launch_bounds__(256) void proj_gemm(
    const float* __restrict__ X, const float* __restrict__ W,
    const float* __restrict__ bias, float* __restrict__ Y, float scale)
{
    __shared__ float4 Xs[32 * 32];  // 32 rows x 128 floats

    const int t = threadIdx.x;
    const float4* Xg = (const float4*)(X + (size_t)blockIdx.x * 32 * 128);
#pragma unroll
    for (int it = 0; it < 4; ++it) Xs[t + it * 256] = Xg[t + it * 256];
    __syncthreads();

    const int col = t & 127;
    const int rg  = t >> 7;  // 0 or 1
    const float4* xs = Xs + rg * 16 * 32;

    float acc[16];
    const float bc = bias[col];
#pragma unroll
    for (int r = 0; r < 16; ++r) acc[r] = bc;

    for (int k4 = 0; k4 < 32; ++k4) {
        const float w0 = W[(4 * k4 + 0) * 128 + col];
        const float w1 = W[(4 * k4 + 1) * 128 + col];
        const float w2 = W[(4 * k4 + 2) * 128 + col];
        const float w3 = W[(4 * k4 + 3) * 128 + col];
#pragma unroll
        for (int r = 0; r < 16; ++r) {
            float4 x = xs[r * 32 + k4];
            acc[r] = fmaf(x.x, w0, acc[r]);
            acc[r] = fmaf(x.y, w1, acc[r]);
            acc[r] = fmaf(x.z, w2, acc[r]);
            acc[r] = fmaf(x.w, w3, acc[r]);
        }
    }

    float* Yg = Y + (size_t)blockIdx.x * 32 * 128;
#pragma unroll
    for (int r = 0; r < 16; ++r) Yg[(rg * 16 + r) * 128 + col] = acc[r] * scale;
}

// ---------------------------------------------------------------------------
// NATTEN edge-index helper (L=64, K=7, dil=2, ns=3), computed inline.
// Returns neighborhood start s and rpb base p for coordinate i.
// ---------------------------------------------------------------------------
__device__ __forceinline__ void natten_idx(int i, int& s, int& p)
{
    if (i < 6) {                 // i - ns*dil < 0
        s = i & 1;
        p = 6 - (i >> 1);
    } else if (i >= 58) {        // i + ns*dil >= L   (L=64, L%dil==0 -> b=0 path)
        s = 50 + (i & 1);        // a + i%dil - K*dil = 64 + i%2 - 14
        p = (63 - i) >> 1;
    } else {
        s = i - 6;
        p = 3;
    }
}

// ---------------------------------------------------------------------------
// Neighborhood attention: one thread per (b, i, j, head).
// qh already includes SCALE. Channel layout: c = head*32 + d.
// ---------------------------------------------------------------------------
__global__ __launch_bounds__(256) void natten_kernel(
    const float* __restrict__ qh, const float* __restrict__ kh,
    const float* __restrict__ vh, const float* __restrict__ rpb,
    float* __restrict__ att)
{
    const int flat = blockIdx.x * 256 + threadIdx.x;  // 0..32767
    const int n = flat & 3;
    const int j = (flat >> 2) & 63;
    const int i = (flat >> 8) & 63;
    const int b = flat >> 14;

    int si, pi0, sj, pj0;
    natten_idx(i, si, pi0);
    natten_idx(j, sj, pj0);

    const size_t pix = (size_t)(b * 4096 + i * 64 + j);
    const float4* qp = (const float4*)(qh + pix * 128 + n * 32);
    float4 qv[8];
#pragma unroll
    for (int t = 0; t < 8; ++t) qv[t] = qp[t];

    float m = -1e30f, l = 0.0f;
    float4 o[8];
#pragma unroll
    for (int t = 0; t < 8; ++t) o[t] = make_float4(0.f, 0.f, 0.f, 0.f);

    const float* rp = rpb + n * 169;  // [13][13]

    for (int ki = 0; ki < 7; ++ki) {
        const int iy = si + 2 * ki;
        const size_t rowbase = ((size_t)(b * 4096 + iy * 64)) * 128 + n * 32;
        const float* rrow = rp + (pi0 + ki) * 13 + pj0;
        for (int kj = 0; kj < 7; ++kj) {
            const int ix = sj + 2 * kj;
            const float4* kp = (const float4*)(kh + rowbase + (size_t)ix * 128);
            float s = rrow[kj];
            float acc = 0.f;
#pragma unroll
            for (int t = 0; t < 8; ++t) {
                float4 kv = kp[t];
                acc = fmaf(qv[t].x, kv.x, acc);
                acc = fmaf(qv[t].y, kv.y, acc);
                acc = fmaf(qv[t].z, kv.z, acc);
                acc = fmaf(qv[t].w, kv.w, acc);
            }
            s += acc;

            const float mnew = fmaxf(m, s);
            const float corr = __expf(m - mnew);   // 0 on first iter (m=-1e30)
            const float p    = __expf(s - mnew);
            m = mnew;
            l = l * corr + p;

            const float4* vp = (const float4*)(vh + rowbase + (size_t)ix * 128);
#pragma unroll
            for (int t = 0; t < 8; ++t) {
                float4 vv = vp[t];
                o[t].x = fmaf(o[t].x, corr, p * vv.x);
                o[t].y = fmaf(o[t].y, corr, p * vv.y);
                o[t].z = fmaf(o[t].z, corr, p * vv.z);
                o[t].w = fmaf(o[t].w, corr, p * vv.w);
            }
        }
    }

    const float inv = 1.0f / l;
    float4* op = (float4*)(att + pix * 128 + n * 32);
#pragma unroll
    for (int t = 0; t < 8; ++t) {
        o[t].x *= inv; o[t].y *= inv; o[t].z *= inv; o[t].w *= inv;
        op[t] = o[t];
    }
}

// ---------------------------------------------------------------------------
extern "C" void kernel_launch(void* const* d_in, const int* in_sizes, int n_in,
                              void* d_out, int out_size, void* d_ws, size_t ws_size,
                              hipStream_t stream)
{
    const float* q   = (const float*)d_in[0];
    const float* k   = (const float*)d_in[1];
    const float* v   = (const float*)d_in[2];
    const float* Wq  = (const float*)d_in[3];
    const float* bq  = (const float*)d_in[4];
    const float* Wk  = (const float*)d_in[5];
    const float* bk  = (const float*)d_in[6];
    const float* Wv  = (const float*)d_in[7];
    const float* bv  = (const float*)d_in[8];
    const float* rpb = (const float*)d_in[9];
    const float* Wo  = (const float*)d_in[10];
    const float* bo  = (const float*)d_in[11];

    float* ws  = (float*)d_ws;
    float* qh  = ws;                       // 8192*128
    float* kh  = ws + (size_t)NPIX * 128;
    float* vh  = ws + (size_t)NPIX * 128 * 2;
    float* att = ws + (size_t)NPIX * 128 * 3;
    float* out = (float*)d_out;

    dim3 gblk(256), gthr(256);
    hipLaunchKernelGGL(proj_gemm, gblk, gthr, 0, stream, q, Wq, bq, qh, SCALE);
    hipLaunchKernelGGL(proj_gemm, gblk, gthr, 0, stream, k, Wk, bk, kh, 1.0f);
    hipLaunchKernelGGL(proj_gemm, gblk, gthr, 0, stream, v, Wv, bv, vh, 1.0f);

    hipLaunchKernelGGL(natten_kernel, dim3(128), dim3(256), 0, stream,
                       qh, kh, vh, rpb, att);

    hipLaunchKernelGGL(proj_gemm, gblk, gthr, 0, stream, att, Wo, bo, out, 1.0f);
}

// Round 2
// 55.369 us; speedup vs baseline: 2.6991x; 2.6991x over previous
//
#include <hip/hip_runtime.h>
#include <hip/hip_bf16.h>
#include <math.h>

// Problem constants
#define BB 2
#define HH 64
#define WW 64
#define DIMC 128
#define NH 4
#define HD 32
#define KS 7
#define DIL 2
#define NPIX (BB * HH * WW)         // 8192 rows
#define SCALE 0.17677669529663687f  // 32^-0.5

// ---------------------------------------------------------------------------
// GEMM body: Y[r,c] = (sum_k X[r,k] * W[k,c] + b[c]) * scale
// One block = 16 rows, 256 threads (2 row-groups x 128 cols), 8 acc/thread.
// ---------------------------------------------------------------------------
__device__ __forceinline__ void gemm_body(
    const float* __restrict__ X, const float* __restrict__ W,
    const float* __restrict__ bias, float* __restrict__ Y, float scale,
    int block)
{
    __shared__ float4 Xs[16 * 32];  // 16 rows x 128 floats

    const int t = threadIdx.x;
    const float4* Xg = (const float4*)(X + (size_t)block * 16 * 128);
    Xs[t]       = Xg[t];
    Xs[t + 256] = Xg[t + 256];
    __syncthreads();

    const int col = t & 127;
    const int rg  = t >> 7;  // 0 or 1
    const float4* xs = Xs + rg * 8 * 32;

    float acc[8];
    const float bc = bias[col];
#pragma unroll
    for (int r = 0; r < 8; ++r) acc[r] = bc;

#pragma unroll 4
    for (int k4 = 0; k4 < 32; ++k4) {
        const float w0 = W[(4 * k4 + 0) * 128 + col];
        const float w1 = W[(4 * k4 + 1) * 128 + col];
        const float w2 = W[(4 * k4 + 2) * 128 + col];
        const float w3 = W[(4 * k4 + 3) * 128 + col];
#pragma unroll
        for (int r = 0; r < 8; ++r) {
            float4 x = xs[r * 32 + k4];
            acc[r] = fmaf(x.x, w0, acc[r]);
            acc[r] = fmaf(x.y, w1, acc[r]);
            acc[r] = fmaf(x.z, w2, acc[r]);
            acc[r] = fmaf(x.w, w3, acc[r]);
        }
    }

    float* Yg = Y + (size_t)block * 16 * 128;
#pragma unroll
    for (int r = 0; r < 8; ++r) Yg[(rg * 8 + r) * 128 + col] = acc[r] * scale;
}

// Fused Q/K/V projection: grid (512, 3)
__global__ __launch_bounds__(256) void qkv_gemm(
    const float* __restrict__ q, const float* __restrict__ k,
    const float* __restrict__ v,
    const float* __restrict__ Wq, const float* __restrict__ Wk,
    const float* __restrict__ Wv,
    const float* __restrict__ bq, const float* __restrict__ bk,
    const float* __restrict__ bv,
    float* __restrict__ qh, float* __restrict__ kh, float* __restrict__ vh)
{
    const int z = blockIdx.y;
    const float* X    = (z == 0) ? q  : (z == 1) ? k  : v;
    const float* W    = (z == 0) ? Wq : (z == 1) ? Wk : Wv;
    const float* bias = (z == 0) ? bq : (z == 1) ? bk : bv;
    float*       Y    = (z == 0) ? qh : (z == 1) ? kh : vh;
    const float scale = (z == 0) ? SCALE : 1.0f;
    gemm_body(X, W, bias, Y, scale, blockIdx.x);
}

__global__ __launch_bounds__(256) void out_gemm(
    const float* __restrict__ X, const float* __restrict__ W,
    const float* __restrict__ bias, float* __restrict__ Y)
{
    gemm_body(X, W, bias, Y, 1.0f, blockIdx.x);
}

// ---------------------------------------------------------------------------
// NATTEN edge-index helper (L=64, K=7, dil=2, ns=3).
// ---------------------------------------------------------------------------
__device__ __forceinline__ void natten_idx(int i, int& s, int& p)
{
    if (i < 6) {                 // i - ns*dil < 0
        s = i & 1;
        p = 6 - (i >> 1);
    } else if (i >= 58) {        // i + ns*dil >= L  (L%dil==0 -> b=0 path)
        s = 50 + (i & 1);        // a + i%dil - K*dil
        p = (63 - i) >> 1;
    } else {
        s = i - 6;
        p = 3;
    }
}

// ---------------------------------------------------------------------------
// Neighborhood attention: 8 lanes per (b,i,j,head); each lane owns 4 channels.
// Score reduce via shfl_xor within the 8-lane group. 262144 threads total.
// ---------------------------------------------------------------------------
__global__ __launch_bounds__(256) void natten_kernel(
    const float* __restrict__ qh, const float* __restrict__ kh,
    const float* __restrict__ vh, const float* __restrict__ rpb,
    float* __restrict__ att)
{
    const int glob = blockIdx.x * 256 + threadIdx.x;  // 0..262143
    const int q4 = glob & 7;          // channel quarter (4 floats)
    const int n  = (glob >> 3) & 3;   // head
    const int j  = (glob >> 5) & 63;
    const int i  = (glob >> 11) & 63;
    const int b  = glob >> 17;

    int si, pi0, sj, pj0;
    natten_idx(i, si, pi0);
    natten_idx(j, sj, pj0);

    const int coff = n * 32 + q4 * 4;
    const size_t pix = (size_t)(b * 4096 + i * 64 + j);
    const float4 qv = *(const float4*)(qh + pix * 128 + coff);

    float m = -1e30f, l = 0.0f;
    float4 o = make_float4(0.f, 0.f, 0.f, 0.f);

    const float* rp = rpb + n * 169;  // [13][13]

    for (int ki = 0; ki < 7; ++ki) {
        const int iy = si + 2 * ki;
        const size_t rowbase = ((size_t)(b * 4096 + iy * 64)) * 128 + coff;
        const float* rrow = rp + (pi0 + ki) * 13 + pj0;
#pragma unroll
        for (int kj = 0; kj < 7; ++kj) {
            const int ix = sj + 2 * kj;
            const float4 kv = *(const float4*)(kh + rowbase + (size_t)ix * 128);
            const float4 vv = *(const float4*)(vh + rowbase + (size_t)ix * 128);

            float s = qv.x * kv.x + qv.y * kv.y + qv.z * kv.z + qv.w * kv.w;
            s += __shfl_xor(s, 1);
            s += __shfl_xor(s, 2);
            s += __shfl_xor(s, 4);
            s += rrow[kj];

            const float mnew = fmaxf(m, s);
            const float corr = __expf(m - mnew);
            const float p    = __expf(s - mnew);
            m = mnew;
            l = fmaf(l, corr, p);

            o.x = fmaf(o.x, corr, p * vv.x);
            o.y = fmaf(o.y, corr, p * vv.y);
            o.z = fmaf(o.z, corr, p * vv.z);
            o.w = fmaf(o.w, corr, p * vv.w);
        }
    }

    const float inv = 1.0f / l;
    float4* op = (float4*)(att + pix * 128 + coff);
    *op = make_float4(o.x * inv, o.y * inv, o.z * inv, o.w * inv);
}

// ---------------------------------------------------------------------------
extern "C" void kernel_launch(void* const* d_in, const int* in_sizes, int n_in,
                              void* d_out, int out_size, void* d_ws, size_t ws_size,
                              hipStream_t stream)
{
    const float* q   = (const float*)d_in[0];
    const float* k   = (const float*)d_in[1];
    const float* v   = (const float*)d_in[2];
    const float* Wq  = (const float*)d_in[3];
    const float* bq  = (const float*)d_in[4];
    const float* Wk  = (const float*)d_in[5];
    const float* bk  = (const float*)d_in[6];
    const float* Wv  = (const float*)d_in[7];
    const float* bv  = (const float*)d_in[8];
    const float* rpb = (const float*)d_in[9];
    const float* Wo  = (const float*)d_in[10];
    const float* bo  = (const float*)d_in[11];

    float* ws  = (float*)d_ws;
    float* qh  = ws;                       // 8192*128
    float* kh  = ws + (size_t)NPIX * 128;
    float* vh  = ws + (size_t)NPIX * 128 * 2;
    float* att = ws + (size_t)NPIX * 128 * 3;
    float* out = (float*)d_out;

    hipLaunchKernelGGL(qkv_gemm, dim3(512, 3), dim3(256), 0, stream,
                       q, k, v, Wq, Wk, Wv, bq, bk, bv, qh, kh, vh);

    hipLaunchKernelGGL(natten_kernel, dim3(1024), dim3(256), 0, stream,
                       qh, kh, vh, rpb, att);

    hipLaunchKernelGGL(out_gemm, dim3(512), dim3(256), 0, stream,
                       att, Wo, bo, out);
}